// Round 7
// baseline (613.867 us; speedup 1.0000x reference)
//
#include <hip/hip_runtime.h>
#include <cstdint>

typedef unsigned short ushort_t;
typedef __bf16 bf16x8 __attribute__((ext_vector_type(8)));
typedef float f32x4 __attribute__((ext_vector_type(4)));
typedef float f32x2 __attribute__((ext_vector_type(2)));

__device__ __forceinline__ unsigned short f2bf(float f) {
  unsigned u = __builtin_bit_cast(unsigned, f);
  u += 0x7FFFu + ((u >> 16) & 1u);   // RNE
  return (unsigned short)(u >> 16);
}
__device__ __forceinline__ float bflo(unsigned u) {  // low bf16 -> f32
  return __builtin_bit_cast(float, u << 16);
}
__device__ __forceinline__ float bfhi(unsigned u) {  // high bf16 -> f32
  return __builtin_bit_cast(float, u & 0xFFFF0000u);
}
// async global->LDS, 16B/lane; LDS dest = wave-uniform base + lane*16
__device__ __forceinline__ void gld16(const void* g, void* l) {
  auto* gp = reinterpret_cast<const __attribute__((address_space(1))) unsigned*>(
      reinterpret_cast<uintptr_t>(g));
  auto* lp = reinterpret_cast<__attribute__((address_space(3))) unsigned*>(
      reinterpret_cast<uintptr_t>(l));
  __builtin_amdgcn_global_load_lds(gp, lp, 16, 0, 0);
}

// ---------------------------------------------------------------------------
// prep_all: UNCHANGED (control).
// ---------------------------------------------------------------------------
__global__ __launch_bounds__(256) void prep_all(
    const float* __restrict__ x, const float* __restrict__ Wq,
    const float* __restrict__ Wk, const float* __restrict__ Wv,
    const float* __restrict__ bq, const float* __restrict__ bk,
    const float* __restrict__ bv, ushort_t* __restrict__ Ax,
    ushort_t* __restrict__ Wt, float* __restrict__ bias) {
  __shared__ ushort_t red[64][65];
  const int b = blockIdx.x;
  const int tid = threadIdx.x;
  if (b < 3072) {
    const int ntile = b % 48, ktile = b / 48;
    const int n0 = ntile * 64, k0 = ktile * 64;
    if (ntile < 16) {
      for (int i = tid; i < 64 * 64; i += 256) {
        const int kk = i >> 6, nn = i & 63;
        const float4 w = *reinterpret_cast<const float4*>(
            Wq + (size_t)(k0 + kk) * 4096 + (size_t)(n0 + nn) * 4);
        red[kk][nn] = f2bf(w.x + w.y + w.z + w.w);
      }
    } else {
      const float* W = (ntile < 32) ? Wk : Wv;
      const int nb = (ntile < 32) ? (n0 - 1024) : (n0 - 2048);
      for (int i = tid; i < 64 * 64; i += 256) {
        const int kk = i >> 6, nn = i & 63;
        red[kk][nn] = f2bf(W[(size_t)(k0 + kk) * 1024 + nb + nn]);
      }
    }
    __syncthreads();
    for (int i = tid; i < 64 * 64; i += 256) {
      const int kk = i & 63, nn = i >> 6;  // coalesced along k
      Wt[(size_t)(n0 + nn) * 4096 + k0 + kk] = red[kk][nn];
    }
  } else if (b < 11264) {
    const size_t i = ((size_t)(b - 3072) * 256 + tid) * 8;
    const float4 a = *reinterpret_cast<const float4*>(x + i);
    const float4 c = *reinterpret_cast<const float4*>(x + i + 4);
    union { ushort_t u[8]; uint4 v; } pk;
    pk.u[0] = f2bf(a.x); pk.u[1] = f2bf(a.y); pk.u[2] = f2bf(a.z); pk.u[3] = f2bf(a.w);
    pk.u[4] = f2bf(c.x); pk.u[5] = f2bf(c.y); pk.u[6] = f2bf(c.z); pk.u[7] = f2bf(c.w);
    *reinterpret_cast<uint4*>(Ax + i) = pk.v;
  } else {
    const int n = (b - 11264) * 256 + tid;  // 0..3071
    float v;
    if (n < 1024) {
      const float4 w = *reinterpret_cast<const float4*>(bq + (size_t)n * 4);
      v = w.x + w.y + w.z + w.w;
    } else if (n < 2048) {
      v = bk[n - 1024];
    } else {
      v = bv[n - 2048];
    }
    bias[n] = v;
  }
}

// ---------------------------------------------------------------------------
// gemm_qkv v7: R4's verified 256x192 / 2Mx2Nx2Khalf geometry and A-staging
// schedule; B moved OUT of LDS into per-wave registers loaded directly from
// L2 (double-buffered, 6 x global dwordx4 per tile = 48 VGPR).
// Cycle model: LDS/tile drops 168 KB -> 96 KB (A frags 64 + A stage 32) =
// ~1130 cy < MFMA 1862 cy -> MFMA becomes the single dominant pipe; B rides
// the VMEM pipe (L2-resident k-slice, ~200cy latency, issued a full tile
// ahead). Correctness: B is registers (no cross-wave hazards); A ledger
// identical to R4 (stage t+1 ahead, vmcnt(0) drain after compute, one raw
// barrier). R5's spill came from 112-reg full-frag dbuf; B-only dbuf is 48.
// ---------------------------------------------------------------------------
#define WAITV0() asm volatile("s_waitcnt vmcnt(0)" ::: "memory")
#define BARRIER()                         \
  do {                                    \
    __builtin_amdgcn_s_barrier();         \
    asm volatile("" ::: "memory");        \
    __builtin_amdgcn_sched_barrier(0);    \
  } while (0)

__global__ __launch_bounds__(512, 2) void gemm_qkv(const ushort_t* __restrict__ A,
                                                   const ushort_t* __restrict__ Bt,
                                                   const float* __restrict__ bias,
                                                   ushort_t* __restrict__ C) {
  // As dbuf 2x32KB at [0,65536); epilogue f32 scratch reuses [0, 99328).
  __shared__ char smem[99328];
  ushort_t* AsBuf = reinterpret_cast<ushort_t*>(smem);  // [2][16384]
  const int tid = threadIdx.x;
  const int lane = tid & 63, wave = tid >> 6;  // 8 waves

  // bijective XCD swizzle (256 blocks, 256 % 8 == 0)
  const int id = blockIdx.x;
  const int wg = (id & 7) * 32 + (id >> 3);
  const int M0 = (wg >> 4) * 256, N0 = (wg & 15) * 192;

  const int rik = lane >> 3;         // row within 8-row chunk
  const int gch = (lane & 7) ^ rik;  // pre-swizzled global k-chunk (involution)
  const ushort_t* aG = A + (size_t)(M0 + wave * 32 + rik) * 4096 + gch * 8;

  const int kh = wave & 1, wq = wave >> 1;   // k-half | output quadrant
  const int wm = wq >> 1, wn = wq & 1;       // 2M x 2N
  const int quad = lane >> 4, l15 = lane & 15;

  // A fragment LDS byte offset (R4-verified, conflict-free)
  const int ch = ((kh * 4 + quad) ^ (l15 & 7)) * 16;
  const int abase = (wm * 128 + l15) * 128 + ch;  // + mi*2048

  // B fragment global base: lane reads 16B of row n = N0+wn*96+ni*16+l15
  // at k = kt*64 + kh*32 + quad*8 .. +7   (16B aligned, L2-resident slice)
  const ushort_t* bD = Bt + (size_t)(N0 + wn * 96 + l15) * 4096 + kh * 32 + quad * 8;

  f32x4 acc[8][6];
  const f32x4 z = {0.f, 0.f, 0.f, 0.f};
#pragma unroll
  for (int mi = 0; mi < 8; ++mi)
#pragma unroll
    for (int ni = 0; ni < 6; ++ni) acc[mi][ni] = z;

  auto stage = [&](int bb, int kt) {
    const int ko = kt * 64;
    ushort_t* asb = AsBuf + bb * 16384;
#pragma unroll
    for (int q = 0; q < 4; ++q)  // A rows wave*32 + q*8 + rik
      gld16(aG + ko + (size_t)q * (8 * 4096), asb + (wave * 4 + q) * 512);
  };
  auto loadB = [&](bf16x8* dst, int kt) {
    const ushort_t* p = bD + kt * 64;
#pragma unroll
    for (int ni = 0; ni < 6; ++ni)
      dst[ni] = *reinterpret_cast<const bf16x8*>(p + ni * (16 * 4096));
  };
  auto compute = [&](int bb, const bf16x8* bfr) {
    const char* ab = reinterpret_cast<const char*>(AsBuf + bb * 16384);
    bf16x8 af[8];
#pragma unroll
    for (int mi = 0; mi < 8; ++mi)
      af[mi] = *reinterpret_cast<const bf16x8*>(ab + abase + mi * 2048);
#pragma unroll
    for (int ni = 0; ni < 6; ++ni) {
      __builtin_amdgcn_s_setprio(1);
#pragma unroll
      for (int mi = 0; mi < 8; ++mi)
        acc[mi][ni] =
            __builtin_amdgcn_mfma_f32_16x16x32_bf16(af[mi], bfr[ni], acc[mi][ni], 0, 0, 0);
      __builtin_amdgcn_s_setprio(0);
    }
  };

  bf16x8 bA[6], bB[6];
  // prologue: stage tile0 -> buf0, load B(0); publish.
  stage(0, 0);
  loadB(bA, 0);
  WAITV0();
  BARRIER();

  for (int t = 0; t < 64; t += 2) {
    // tile t: A in buf0, B in bA. Prefetch t+1 (buf1, bB).
    stage(1, t + 1);      // t+1 <= 63 always
    loadB(bB, t + 1);
    compute(0, bA);
    WAITV0();             // stage(t+1)+loadB(t+1) had the whole tile to land
    BARRIER();
    // tile t+1: A in buf1, B in bB. Prefetch t+2 (buf0, bA).
    if (t + 2 < 64) {
      stage(0, t + 2);
      loadB(bA, t + 2);
    }
    compute(1, bB);
    WAITV0();
    BARRIER();
  }

  // ---- epilogue: reduce k-halves via LDS, add bias, store bf16 ----
  float* scr = reinterpret_cast<float*>(smem);
  const int slot = (wq * 64 + lane) * 97;  // 96 floats + 1 pad -> conflict-free
#pragma unroll
  for (int p = 0; p < 2; ++p) {
    __syncthreads();
    if (kh == 1) {
#pragma unroll
      for (int mi = 0; mi < 4; ++mi)
#pragma unroll
        for (int ni = 0; ni < 6; ++ni)
#pragma unroll
          for (int r = 0; r < 4; ++r)
            scr[slot + (mi * 6 + ni) * 4 + r] = acc[p * 4 + mi][ni][r];
    }
    __syncthreads();
    if (kh == 0) {
#pragma unroll
      for (int ni = 0; ni < 6; ++ni) {
        const int cc = N0 + wn * 96 + ni * 16 + l15;
        const float bn = bias[cc];
#pragma unroll
        for (int mi = 0; mi < 4; ++mi) {
          const int gmi = p * 4 + mi;
          const int r0 = M0 + wm * 128 + gmi * 16 + quad * 4;
#pragma unroll
          for (int r = 0; r < 4; ++r)
            C[(size_t)(r0 + r) * 3072 + cc] =
                f2bf(acc[gmi][ni][r] + scr[slot + (mi * 6 + ni) * 4 + r] + bn);
        }
      }
    }
  }
}

// ---------------------------------------------------------------------------
// attn_tok v4: UNCHANGED from R6 (verified; gld16 staging, no barrier,
// packed f32x2 arithmetic).
// ---------------------------------------------------------------------------
__global__ __launch_bounds__(256, 4) void attn_tok(const ushort_t* __restrict__ C,
                                                   float* __restrict__ out) {
  __shared__ uint4 kv4[4][256];  // [wave][k rows 0..127 | v rows 128..255]
  const int tid = threadIdx.x;
  const int lane = tid & 63, wv = tid >> 6;
  const int t = blockIdx.x * 4 + wv;
  const ushort_t* Crow = C + (size_t)t * 3072;

  // stage 4 KB of K|V via async global->LDS: lane's 16B at base + lane*16
  const ushort_t* kvg = Crow + 1024;
#pragma unroll
  for (int r = 0; r < 4; ++r)
    gld16(kvg + r * 512 + lane * 8, &kv4[wv][r * 64]);

  const uint4 q01 = *reinterpret_cast<const uint4*>(Crow + lane * 16);
  const uint4 q23 = *reinterpret_cast<const uint4*>(Crow + lane * 16 + 8);
  f32x2 q2[8];
  q2[0] = f32x2{bflo(q01.x), bflo(q23.x)};
  q2[1] = f32x2{bfhi(q01.x), bfhi(q23.x)};
  q2[2] = f32x2{bflo(q01.y), bflo(q23.y)};
  q2[3] = f32x2{bfhi(q01.y), bfhi(q23.y)};
  q2[4] = f32x2{bflo(q01.z), bflo(q23.z)};
  q2[5] = f32x2{bfhi(q01.z), bfhi(q23.z)};
  q2[6] = f32x2{bflo(q01.w), bflo(q23.w)};
  q2[7] = f32x2{bfhi(q01.w), bfhi(q23.w)};

  WAITV0();  // own wave's 4 staging loads landed; no cross-wave sharing

  const uint4* kvw = kv4[wv];
  const float sc = 0.08838834764831845f;  // 1/sqrt(128)
  f32x2 o2[8];
#pragma unroll
  for (int j = 0; j < 8; ++j) o2[j] = f32x2{0.f, 0.f};
  f32x2 lsum = f32x2{0.f, 0.f};

#pragma unroll 2
  for (int e = 0; e < 128; ++e) {
    const uint4 kr = kvw[e];
    float kf[8];
    kf[0] = bflo(kr.x); kf[1] = bfhi(kr.x); kf[2] = bflo(kr.y); kf[3] = bfhi(kr.y);
    kf[4] = bflo(kr.z); kf[5] = bfhi(kr.z); kf[6] = bflo(kr.w); kf[7] = bfhi(kr.w);
    f32x2 s = f32x2{0.f, 0.f};
#pragma unroll
    for (int j = 0; j < 8; ++j) s += q2[j] * kf[j];
    const f32x2 p = f32x2{__expf(s.x * sc), __expf(s.y * sc)};
    lsum += p;
    const uint4 vr = kvw[128 + e];
    float vf[8];
    vf[0] = bflo(vr.x); vf[1] = bfhi(vr.x); vf[2] = bflo(vr.y); vf[3] = bfhi(vr.y);
    vf[4] = bflo(vr.z); vf[5] = bfhi(vr.z); vf[6] = bflo(vr.w); vf[7] = bfhi(vr.w);
#pragma unroll
    for (int j = 0; j < 8; ++j) o2[j] += p * vf[j];
  }

  const float i0 = 1.f / lsum.x, i1 = 1.f / lsum.y;
  float4* dst = reinterpret_cast<float4*>(out + (size_t)t * 4096 + (size_t)lane * 64);
#pragma unroll
  for (int j = 0; j < 8; ++j) {
    const float w = o2[j].x * i0;
    dst[j] = make_float4(w, w, w, w);
  }
#pragma unroll
  for (int j = 0; j < 8; ++j) {
    const float w = o2[j].y * i1;
    dst[8 + j] = make_float4(w, w, w, w);
  }
}

extern "C" void kernel_launch(void* const* d_in, const int* in_sizes, int n_in,
                              void* d_out, int out_size, void* d_ws, size_t ws_size,
                              hipStream_t stream) {
  const float* x  = (const float*)d_in[0];  // [2,2048,4096] fp32
  const float* Wq = (const float*)d_in[1];  // [4096,128,32]
  const float* bq = (const float*)d_in[2];  // [128,32]
  const float* Wk = (const float*)d_in[3];  // [4096,128,8]
  const float* bk = (const float*)d_in[4];  // [128,8]
  const float* Wv = (const float*)d_in[5];  // [4096,128,8]
  const float* bv = (const float*)d_in[6];  // [128,8]
  float* out = (float*)d_out;               // [4096][4096] fp32 = 64 MB

  // d_out doubles as scratch until attn_tok overwrites it:
  //   [0,32M): Ax bf16; [32M,56M): Wt bf16; [56M,+12K): bias fp32.
  // d_ws: Cmat bf16 [4096][3072] (24 MB).
  ushort_t* Ax = (ushort_t*)d_out;
  ushort_t* Wt = Ax + (size_t)4096 * 4096;
  float* bias = (float*)(Wt + (size_t)3072 * 4096);
  ushort_t* Cmat = (ushort_t*)d_ws;

  prep_all<<<dim3(11276), 256, 0, stream>>>(x, Wq, Wk, Wv, bq, bk, bv, Ax, Wt, bias);
  gemm_qkv<<<dim3(256), 512, 0, stream>>>(Ax, Wt, bias, Cmat);
  attn_tok<<<dim3(1024), 256, 0, stream>>>(Cmat, out);
}